// Round 4
// baseline (388.811 us; speedup 1.0000x reference)
//
#include <hip/hip_runtime.h>

#define N_NODES 50000
#define N_EDGES 600000
#define F 128
#define NBIN 400000      // rel*N_NODES + dst bins
#define NBS1 1563        // scan-pass-1 blocks (covers 400128)

// ---------- ws layout (16-aligned) ----------
#define WT_OFF   0                 // 294,912 B   bf16 W [r][o][i-swizzled], r=8 is loop_weight
#define H2_OFF   294912            // 12,800,000  bf16 h
#define GATE_OFF 13094912          // 1,600,000   sigmoid gates [r][n]
#define CNT_OFF  14694912          // 1,600,512   histogram (drained by scatter)
#define EXCL_OFF 16295424          // 1,600,512   per-block exclusive scan partials
#define BSUM_OFF 17895936          // 6,400       block sums (scanned)
#define REC_OFF  17902336          // 4,800,000   {src, scale} per edge, (rel,dst)-sorted
#define WS_NEED  ((size_t)22702336)

typedef __attribute__((ext_vector_type(8))) short short8;
typedef __attribute__((ext_vector_type(4))) float floatx4;

__device__ inline unsigned short f32_to_bf16(float f) {
    unsigned u = __float_as_uint(f);
    unsigned r = u + 0x7fff + ((u >> 16) & 1);
    return (unsigned short)(r >> 16);
}
__device__ inline float bf16lo(unsigned m) { return __uint_as_float(m << 16); }
__device__ inline float bf16hi(unsigned m) { return __uint_as_float(m & 0xffff0000u); }
__device__ inline float sigmoidf(float x) { return 1.f / (1.f + __expf(-x)); }

// ---------- weights (+loop_weight as r=8) -> bf16 [r][o][granule-swizzled i] ----------
__global__ void k_prep_w(const float* __restrict__ W, const float* __restrict__ LW,
                         unsigned short* __restrict__ Wt) {
    int idx = blockIdx.x * 256 + threadIdx.x;
    if (idx >= 9 * 128 * 128) return;
    int r = idx >> 14;
    int rem = idx & 16383;
    int i = rem >> 7, o = rem & 127;
    float v = (r < 8) ? W[(r << 14) + (i << 7) + o] : LW[(i << 7) + o];
    int g = (i >> 3) ^ (o & 7);          // 16B-granule XOR swizzle keyed on o
    Wt[(r << 14) + (o << 7) + (g << 3) + (i & 7)] = f32_to_bf16(v);
}

// ---------- h->bf16, gates, and (rel,dst) histogram fused ----------
__global__ void k_prep(const float* __restrict__ h, const float* __restrict__ gw,
                       const int* __restrict__ dst, const int* __restrict__ rel,
                       unsigned short* __restrict__ h2, float* __restrict__ gate,
                       int* __restrict__ cnt) {
    int e = blockIdx.x * 256 + threadIdx.x;
    if (e < N_EDGES) atomicAdd(&cnt[rel[e] * N_NODES + dst[e]], 1);

    int wave = threadIdx.x >> 6, lane = threadIdx.x & 63;
    int n = blockIdx.x * 4 + wave;            // grid 12500 -> exactly 50000
    float2 hv = *(const float2*)(h + (size_t)n * F + lane * 2);
    unsigned val = (unsigned)f32_to_bf16(hv.x) | ((unsigned)f32_to_bf16(hv.y) << 16);
    *(unsigned*)(h2 + (size_t)n * F + lane * 2) = val;
    #pragma unroll
    for (int r = 0; r < 8; ++r) {
        float2 wv = *(const float2*)(gw + r * F + lane * 2);
        float p = hv.x * wv.x + hv.y * wv.y;
        #pragma unroll
        for (int off = 32; off; off >>= 1) p += __shfl_xor(p, off);
        if (lane == 0) gate[r * N_NODES + n] = sigmoidf(p);
    }
}

// ---------- scan pass 1: per-256 block exclusive partials + block sums ----------
__global__ void k_s1(const int* __restrict__ cnt, int* __restrict__ excl,
                     int* __restrict__ bsum) {
    __shared__ int wsum[4];
    int g = blockIdx.x * 256 + threadIdx.x;
    int wave = threadIdx.x >> 6, lane = threadIdx.x & 63;
    int v = (g < NBIN) ? cnt[g] : 0;
    int x = v;
    #pragma unroll
    for (int off = 1; off < 64; off <<= 1) {
        int t = __shfl_up(x, off);
        if (lane >= off) x += t;
    }
    if (lane == 63) wsum[wave] = x;
    __syncthreads();
    int pre = 0;
    #pragma unroll
    for (int w = 0; w < 4; ++w) if (w < wave) pre += wsum[w];
    if (g < NBIN) excl[g] = x + pre - v;
    if (threadIdx.x == 255) bsum[blockIdx.x] = x + pre;
}

// ---------- scan pass 2: scan the 1563 block sums (single block) ----------
__global__ void k_s2(int* __restrict__ bsum) {
    __shared__ int sh[256];
    int t = threadIdx.x;
    int v[7];
    int s = 0;
    #pragma unroll
    for (int j = 0; j < 7; ++j) {
        int idx = t * 7 + j;
        v[j] = (idx < NBS1) ? bsum[idx] : 0;
        s += v[j];
    }
    sh[t] = s;
    __syncthreads();
    #pragma unroll
    for (int off = 1; off < 256; off <<= 1) {
        int tt = (t >= off) ? sh[t - off] : 0;
        __syncthreads();
        sh[t] += tt;
        __syncthreads();
    }
    int run = sh[t] - s;
    #pragma unroll
    for (int j = 0; j < 7; ++j) {
        int idx = t * 7 + j;
        if (idx < NBS1) bsum[idx] = run;
        run += v[j];
    }
}

// ---------- scatter into (rel,dst)-sorted rec; drains cnt via atomicSub ----------
__global__ void k_scatter(const int* __restrict__ src, const int* __restrict__ dst,
                          const int* __restrict__ rel, const float* __restrict__ norm,
                          const float* __restrict__ gate,
                          const int* __restrict__ excl, const int* __restrict__ bsum,
                          int* __restrict__ cnt, int2* __restrict__ rec) {
    int e = blockIdx.x * 256 + threadIdx.x;
    if (e >= N_EDGES) return;
    int d = dst[e], r = rel[e], s = src[e];
    int bin = r * N_NODES + d;
    int base = excl[bin] + bsum[bin >> 8];
    int old = atomicSub(&cnt[bin], 1);
    float sc = norm[e] * gate[r * N_NODES + s];
    rec[base + old - 1] = make_int2(s, __float_as_int(sc));
}

// ---------- fused: per-64-node tile, aggregate into LDS per relation, MFMA, epilogue ----------
__global__ __launch_bounds__(256) void k_fused(const unsigned short* __restrict__ h2,
                                               const unsigned short* __restrict__ Wt,
                                               const int2* __restrict__ rec,
                                               const int* __restrict__ excl,
                                               const int* __restrict__ bsum,
                                               const float* __restrict__ bias,
                                               float* __restrict__ out) {
    __shared__ unsigned short sA[64 * 128];    // 16 KB, swizzled bf16 A tile
    __shared__ unsigned short sB[128 * 128];   // 32 KB, swizzled bf16 W_kb
    int tid = threadIdx.x;
    int wave = tid >> 6, lane = tid & 63;
    int lrow = lane & 15, quad = lane >> 4;
    int nb = blockIdx.x * 64;                  // grid 782 -> rows up to 50047 (padded)
    int n0w = nb + wave * 16;

    floatx4 acc[8];
    #pragma unroll
    for (int nt = 0; nt < 8; ++nt) acc[nt] = (floatx4){0.f, 0.f, 0.f, 0.f};

    for (int kb = 0; kb < 9; ++kb) {
        __syncthreads();   // previous MFMA reads of sA/sB complete
        // stage W_kb (global already granule-swizzled -> flat copy)
        #pragma unroll
        for (int it = 0; it < 8; ++it) {
            int G = it * 256 + tid;
            *(uint4*)(&sB[G * 8]) = *(const uint4*)(Wt + (kb << 14) + G * 8);
        }
        if (kb < 8) {
            // segment bounds for this wave's 16 rows (+1)
            int b = 0;
            if (lane < 17) {
                int idx = kb * N_NODES + n0w + lane;
                b = (idx < NBIN) ? (excl[idx] + bsum[idx >> 8]) : N_EDGES;
            }
            int b0 = __shfl(b, 0);
            int degT = __shfl(b, 16) - b0;
            int rs = 0, rscl = 0;
            if (lane < degT) {                  // batch-load up to 64 edge records
                int2 rc = rec[b0 + lane];
                rs = rc.x; rscl = rc.y;
            }
            for (int rr = 0; rr < 16; ++rr) {
                int s = __shfl(b, rr), e = __shfl(b, rr + 1);
                float a0 = 0.f, a1 = 0.f;
                for (int j = s; j < e; ++j) {
                    int off = j - b0;
                    int sj; float sc;
                    if (off < 64) {             // wave-uniform branch
                        sj = __shfl(rs, off);
                        sc = __int_as_float(__shfl(rscl, off));
                    } else {                    // rare overflow: uniform direct load
                        int2 rc = rec[j];
                        sj = rc.x; sc = __int_as_float(rc.y);
                    }
                    unsigned m = *(const unsigned*)(h2 + (size_t)sj * F + lane * 2);
                    a0 += sc * bf16lo(m);
                    a1 += sc * bf16hi(m);
                }
                int row = wave * 16 + rr;
                unsigned val = (unsigned)f32_to_bf16(a0) | ((unsigned)f32_to_bf16(a1) << 16);
                ((unsigned*)sA)[row * 64 + (((lane >> 2) ^ (row & 7)) << 2) + (lane & 3)] = val;
            }
        } else {
            // kb=8 self-loop: stage h2 rows directly (swizzled)
            #pragma unroll
            for (int it = 0; it < 4; ++it) {
                int G = it * 256 + tid;         // 0..1023
                int row = G >> 4, gr = G & 15;
                int node = nb + row;
                uint4 v;
                if (node < N_NODES) v = *(const uint4*)(h2 + (size_t)node * F + gr * 8);
                else { v.x = 0; v.y = 0; v.z = 0; v.w = 0; }
                *(uint4*)(&sA[row * 128 + ((gr ^ (row & 7)) << 3)]) = v;
            }
        }
        __syncthreads();
        #pragma unroll
        for (int kt = 0; kt < 4; ++kt) {
            int sw = (((kt * 4 + quad) ^ (lrow & 7)) << 3);
            short8 a = *(const short8*)(&sA[(wave * 16 + lrow) * 128 + sw]);
            #pragma unroll
            for (int nt = 0; nt < 8; ++nt) {
                short8 bb = *(const short8*)(&sB[(nt * 16 + lrow) * 128 + sw]);
                acc[nt] = __builtin_amdgcn_mfma_f32_16x16x32_bf16(a, bb, acc[nt], 0, 0, 0);
            }
        }
    }
    // epilogue: bias + relu, one store per output element
    #pragma unroll
    for (int nt = 0; nt < 8; ++nt) {
        int col = nt * 16 + lrow;
        float bv = bias[col];
        #pragma unroll
        for (int g = 0; g < 4; ++g) {
            int row = nb + wave * 16 + quad * 4 + g;
            if (row < N_NODES)
                out[(size_t)row * F + col] = fmaxf(acc[nt][g] + bv, 0.f);
        }
    }
}

// ---------- ws-free safety fallback ----------
__global__ void k_edges_fb(const float* __restrict__ h, const float* __restrict__ W,
                           const float* __restrict__ gw, const float* __restrict__ norm,
                           const int* __restrict__ src, const int* __restrict__ dst,
                           const int* __restrict__ rel, float* __restrict__ out) {
    int wave = threadIdx.x >> 6, lane = threadIdx.x & 63;
    int e = blockIdx.x * 4 + wave;
    if (e >= N_EDGES) return;
    int s = src[e], d = dst[e], r = rel[e];
    float2 hv = *(const float2*)(h + (size_t)s * F + lane * 2);
    float2 gv = *(const float2*)(gw + r * F + lane * 2);
    float p = hv.x * gv.x + hv.y * gv.y;
    #pragma unroll
    for (int off = 32; off; off >>= 1) p += __shfl_xor(p, off);
    float scale = norm[e] * sigmoidf(p);
    const float* wr = W + ((size_t)r << 14);
    float a0 = 0.f, a1 = 0.f;
    for (int i2 = 0; i2 < 64; ++i2) {
        float x0 = __shfl(hv.x, i2), x1 = __shfl(hv.y, i2);
        a0 += x0 * wr[(2 * i2) * F + lane]      + x1 * wr[(2 * i2 + 1) * F + lane];
        a1 += x0 * wr[(2 * i2) * F + 64 + lane] + x1 * wr[(2 * i2 + 1) * F + 64 + lane];
    }
    unsafeAtomicAdd(out + (size_t)d * F + lane,      a0 * scale);
    unsafeAtomicAdd(out + (size_t)d * F + 64 + lane, a1 * scale);
}

__global__ void k_final_fb(const float* __restrict__ h, const float* __restrict__ LW,
                           const float* __restrict__ bias, float* __restrict__ out) {
    int wave = threadIdx.x >> 6, lane = threadIdx.x & 63;
    int n = blockIdx.x * 4 + wave;
    if (n >= N_NODES) return;
    float2 hv = *(const float2*)(h + (size_t)n * F + lane * 2);
    float a0 = 0.f, a1 = 0.f;
    for (int i2 = 0; i2 < 64; ++i2) {
        float x0 = __shfl(hv.x, i2), x1 = __shfl(hv.y, i2);
        a0 += x0 * LW[(2 * i2) * F + lane]      + x1 * LW[(2 * i2 + 1) * F + lane];
        a1 += x0 * LW[(2 * i2) * F + 64 + lane] + x1 * LW[(2 * i2 + 1) * F + 64 + lane];
    }
    float* op = out + (size_t)n * F;
    op[lane]      = fmaxf(op[lane]      + bias[lane]      + a0, 0.f);
    op[64 + lane] = fmaxf(op[64 + lane] + bias[64 + lane] + a1, 0.f);
}

extern "C" void kernel_launch(void* const* d_in, const int* in_sizes, int n_in,
                              void* d_out, int out_size, void* d_ws, size_t ws_size,
                              hipStream_t stream) {
    const float* h    = (const float*)d_in[0];
    const float* W    = (const float*)d_in[1];
    const float* gw   = (const float*)d_in[2];
    const float* bias = (const float*)d_in[3];
    const float* lw   = (const float*)d_in[4];
    const float* norm = (const float*)d_in[5];
    const int* src    = (const int*)d_in[6];
    const int* dst    = (const int*)d_in[7];
    const int* rel    = (const int*)d_in[8];
    float* out = (float*)d_out;

    if (ws_size >= WS_NEED) {
        unsigned short* Wt   = (unsigned short*)((char*)d_ws + WT_OFF);
        unsigned short* h2   = (unsigned short*)((char*)d_ws + H2_OFF);
        float*          gate = (float*)((char*)d_ws + GATE_OFF);
        int*            cnt  = (int*)((char*)d_ws + CNT_OFF);
        int*            excl = (int*)((char*)d_ws + EXCL_OFF);
        int*            bsum = (int*)((char*)d_ws + BSUM_OFF);
        int2*           rec  = (int2*)((char*)d_ws + REC_OFF);

        hipMemsetAsync(cnt, 0, 400128 * sizeof(int), stream);
        k_prep_w<<<576, 256, 0, stream>>>(W, lw, Wt);
        k_prep<<<12500, 256, 0, stream>>>(h, gw, dst, rel, h2, gate, cnt);
        k_s1<<<NBS1, 256, 0, stream>>>(cnt, excl, bsum);
        k_s2<<<1, 256, 0, stream>>>(bsum);
        k_scatter<<<2344, 256, 0, stream>>>(src, dst, rel, norm, gate, excl, bsum, cnt, rec);
        k_fused<<<782, 256, 0, stream>>>(h2, Wt, rec, excl, bsum, bias, out);
    } else {
        hipMemsetAsync(d_out, 0, (size_t)out_size * sizeof(float), stream);
        k_edges_fb<<<150000, 256, 0, stream>>>(h, W, gw, norm, src, dst, rel, out);
        k_final_fb<<<12500, 256, 0, stream>>>(h, lw, bias, out);
    }
}

// Round 5
// 291.883 us; speedup vs baseline: 1.3321x; 1.3321x over previous
//
#include <hip/hip_runtime.h>

#define N_NODES 50000
#define N_EDGES 600000
#define F 128
#define NBIN 400000      // rel*N_NODES + dst bins
#define NBS1 1563        // scan-pass-1 blocks (covers 400128)

// ---------- ws layout (16-aligned) ----------
#define WT_OFF   0                 // 294,912 B   bf16 W [r][o][i], r=8 is loop_weight
#define H2_OFF   294912            // 12,800,000  bf16 h
#define GATE_OFF 13094912          // 1,600,000   sigmoid gates [r][n]
#define CNT_OFF  14694912          // 1,600,512   histogram (drained by scatter)
#define EXCL_OFF 16295424          // 1,600,512   per-block exclusive scan partials
#define BSUM_OFF 17895936          // 6,400       block sums (scanned)
#define REC_OFF  17902336          // 4,800,000   {src, scale} per edge, (rel,dst)-sorted
#define WS_NEED  ((size_t)22702336)

#define LDA 136   // padded short stride: 272B rows, 16B-aligned, 2-way bank aliasing (free)

typedef __attribute__((ext_vector_type(8))) short short8;
typedef __attribute__((ext_vector_type(4))) float floatx4;

__device__ inline unsigned short f32_to_bf16(float f) {
    unsigned u = __float_as_uint(f);
    unsigned r = u + 0x7fff + ((u >> 16) & 1);
    return (unsigned short)(r >> 16);
}
__device__ inline float bf16lo(unsigned m) { return __uint_as_float(m << 16); }
__device__ inline float bf16hi(unsigned m) { return __uint_as_float(m & 0xffff0000u); }
__device__ inline float sigmoidf(float x) { return 1.f / (1.f + __expf(-x)); }

// ---------- weights (+loop_weight as r=8) -> bf16 [r][o][i] ----------
__global__ void k_prep_w(const float* __restrict__ W, const float* __restrict__ LW,
                         unsigned short* __restrict__ Wt) {
    int idx = blockIdx.x * 256 + threadIdx.x;
    if (idx >= 9 * 128 * 128) return;
    int r = idx >> 14;
    int rem = idx & 16383;
    int i = rem >> 7, o = rem & 127;
    float v = (r < 8) ? W[(r << 14) + (i << 7) + o] : LW[(i << 7) + o];
    Wt[(r << 14) + (o << 7) + i] = f32_to_bf16(v);
}

// ---------- h->bf16, gates, and (rel,dst) histogram fused ----------
__global__ void k_prep(const float* __restrict__ h, const float* __restrict__ gw,
                       const int* __restrict__ dst, const int* __restrict__ rel,
                       unsigned short* __restrict__ h2, float* __restrict__ gate,
                       int* __restrict__ cnt) {
    int e = blockIdx.x * 256 + threadIdx.x;
    if (e < N_EDGES) atomicAdd(&cnt[rel[e] * N_NODES + dst[e]], 1);

    int wave = threadIdx.x >> 6, lane = threadIdx.x & 63;
    int n = blockIdx.x * 4 + wave;            // grid 12500 -> exactly 50000
    float2 hv = *(const float2*)(h + (size_t)n * F + lane * 2);
    unsigned val = (unsigned)f32_to_bf16(hv.x) | ((unsigned)f32_to_bf16(hv.y) << 16);
    *(unsigned*)(h2 + (size_t)n * F + lane * 2) = val;
    #pragma unroll
    for (int r = 0; r < 8; ++r) {
        float2 wv = *(const float2*)(gw + r * F + lane * 2);
        float p = hv.x * wv.x + hv.y * wv.y;
        #pragma unroll
        for (int off = 32; off; off >>= 1) p += __shfl_xor(p, off);
        if (lane == 0) gate[r * N_NODES + n] = sigmoidf(p);
    }
}

// ---------- scan pass 1 ----------
__global__ void k_s1(const int* __restrict__ cnt, int* __restrict__ excl,
                     int* __restrict__ bsum) {
    __shared__ int wsum[4];
    int g = blockIdx.x * 256 + threadIdx.x;
    int wave = threadIdx.x >> 6, lane = threadIdx.x & 63;
    int v = (g < NBIN) ? cnt[g] : 0;
    int x = v;
    #pragma unroll
    for (int off = 1; off < 64; off <<= 1) {
        int t = __shfl_up(x, off);
        if (lane >= off) x += t;
    }
    if (lane == 63) wsum[wave] = x;
    __syncthreads();
    int pre = 0;
    #pragma unroll
    for (int w = 0; w < 4; ++w) if (w < wave) pre += wsum[w];
    if (g < NBIN) excl[g] = x + pre - v;
    if (threadIdx.x == 255) bsum[blockIdx.x] = x + pre;
}

// ---------- scan pass 2 ----------
__global__ void k_s2(int* __restrict__ bsum) {
    __shared__ int sh[256];
    int t = threadIdx.x;
    int v[7];
    int s = 0;
    #pragma unroll
    for (int j = 0; j < 7; ++j) {
        int idx = t * 7 + j;
        v[j] = (idx < NBS1) ? bsum[idx] : 0;
        s += v[j];
    }
    sh[t] = s;
    __syncthreads();
    #pragma unroll
    for (int off = 1; off < 256; off <<= 1) {
        int tt = (t >= off) ? sh[t - off] : 0;
        __syncthreads();
        sh[t] += tt;
        __syncthreads();
    }
    int run = sh[t] - s;
    #pragma unroll
    for (int j = 0; j < 7; ++j) {
        int idx = t * 7 + j;
        if (idx < NBS1) bsum[idx] = run;
        run += v[j];
    }
}

// ---------- scatter into (rel,dst)-sorted rec; drains cnt via atomicSub ----------
__global__ void k_scatter(const int* __restrict__ src, const int* __restrict__ dst,
                          const int* __restrict__ rel, const float* __restrict__ norm,
                          const float* __restrict__ gate,
                          const int* __restrict__ excl, const int* __restrict__ bsum,
                          int* __restrict__ cnt, int2* __restrict__ rec) {
    int e = blockIdx.x * 256 + threadIdx.x;
    if (e >= N_EDGES) return;
    int d = dst[e], r = rel[e], s = src[e];
    int bin = r * N_NODES + d;
    int base = excl[bin] + bsum[bin >> 8];
    int old = atomicSub(&cnt[bin], 1);
    float sc = norm[e] * gate[r * N_NODES + s];
    rec[base + old - 1] = make_int2(s, __float_as_int(sc));
}

// ---------- fused: 64-node tile, 16 waves; agg->LDS per relation, MFMA, epilogue ----------
// wave w: agg rows w*4..w*4+3; MFMA sub-tile rows (w>>2)*16, cols (w&3)*32.
__global__ __launch_bounds__(1024, 8) void k_fused(const unsigned short* __restrict__ h2,
                                                   const unsigned short* __restrict__ Wt,
                                                   const int2* __restrict__ rec,
                                                   const int* __restrict__ excl,
                                                   const int* __restrict__ bsum,
                                                   const float* __restrict__ bias,
                                                   float* __restrict__ out) {
    __shared__ unsigned short sA[64 * LDA];    // 17 KB
    __shared__ unsigned short sB[128 * LDA];   // 34 KB
    int tid = threadIdx.x;
    int w = tid >> 6, lane = tid & 63;
    int lrow = lane & 15, quad = lane >> 4;
    int nb = blockIdx.x * 64;                  // grid 782 covers 50048 rows
    int mblk = w >> 2;                         // A-row block (16 rows)
    int nblk = w & 3;                          // B-col block (32 cols)

    floatx4 acc[2];
    acc[0] = (floatx4){0.f, 0.f, 0.f, 0.f};
    acc[1] = (floatx4){0.f, 0.f, 0.f, 0.f};

    for (int kb = 0; kb < 9; ++kb) {
        __syncthreads();   // previous MFMA reads of sA/sB complete
        // stage W_kb: 2048 granules (16B) over 1024 threads
        #pragma unroll
        for (int it = 0; it < 2; ++it) {
            int G = it * 1024 + tid;
            int row = G >> 4, gr = G & 15;
            *(uint4*)(&sB[row * LDA + gr * 8]) = *(const uint4*)(Wt + (kb << 14) + G * 8);
        }
        if (kb < 8) {
            // segment bounds for this wave's 4 rows (+1)
            int b = 0;
            if (lane < 5) {
                int node = nb + w * 4 + lane;
                int nd = (node < N_NODES) ? node : N_NODES;
                int eff = kb * N_NODES + nd;
                b = (eff < NBIN) ? (excl[eff] + bsum[eff >> 8]) : N_EDGES;
            }
            int b0 = __shfl(b, 0);
            int degT = __shfl(b, 4) - b0;
            int rs = 0, rscl = 0;
            if (lane < degT) {                  // batch-load up to 64 edge records
                int2 rc = rec[b0 + lane];
                rs = rc.x; rscl = rc.y;
            }
            #pragma unroll
            for (int rr = 0; rr < 4; ++rr) {
                int s = __shfl(b, rr), e = __shfl(b, rr + 1);
                float a0 = 0.f, a1 = 0.f;
                for (int j = s; j < e; ++j) {
                    int off = j - b0;
                    int sj; float sc;
                    if (off < 64) {             // wave-uniform branch
                        sj = __shfl(rs, off);
                        sc = __int_as_float(__shfl(rscl, off));
                    } else {                    // rare overflow: uniform direct load
                        int2 rc = rec[j];
                        sj = rc.x; sc = __int_as_float(rc.y);
                    }
                    unsigned m = *(const unsigned*)(h2 + (size_t)sj * F + lane * 2);
                    a0 += sc * bf16lo(m);
                    a1 += sc * bf16hi(m);
                }
                int row = w * 4 + rr;
                unsigned val = (unsigned)f32_to_bf16(a0) | ((unsigned)f32_to_bf16(a1) << 16);
                ((unsigned*)sA)[row * (LDA / 2) + lane] = val;
            }
        } else {
            // kb=8 self-loop: stage h2 rows directly (1024 granules)
            int row = tid >> 4, gr = tid & 15;
            int node = nb + row;
            uint4 v;
            if (node < N_NODES) v = *(const uint4*)(h2 + (size_t)node * F + gr * 8);
            else { v.x = 0; v.y = 0; v.z = 0; v.w = 0; }
            *(uint4*)(&sA[row * LDA + gr * 8]) = v;
        }
        __syncthreads();
        #pragma unroll
        for (int kt = 0; kt < 4; ++kt) {
            short8 a = *(const short8*)(&sA[(mblk * 16 + lrow) * LDA + kt * 32 + quad * 8]);
            #pragma unroll
            for (int nt = 0; nt < 2; ++nt) {
                short8 bb = *(const short8*)(&sB[(nblk * 32 + nt * 16 + lrow) * LDA + kt * 32 + quad * 8]);
                acc[nt] = __builtin_amdgcn_mfma_f32_16x16x32_bf16(a, bb, acc[nt], 0, 0, 0);
            }
        }
    }
    // epilogue: bias + relu
    #pragma unroll
    for (int nt = 0; nt < 2; ++nt) {
        int col = nblk * 32 + nt * 16 + lrow;
        float bv = bias[col];
        #pragma unroll
        for (int g = 0; g < 4; ++g) {
            int row = nb + mblk * 16 + quad * 4 + g;
            if (row < N_NODES)
                out[(size_t)row * F + col] = fmaxf(acc[nt][g] + bv, 0.f);
        }
    }
}

// ---------- ws-free safety fallback ----------
__global__ void k_edges_fb(const float* __restrict__ h, const float* __restrict__ W,
                           const float* __restrict__ gw, const float* __restrict__ norm,
                           const int* __restrict__ src, const int* __restrict__ dst,
                           const int* __restrict__ rel, float* __restrict__ out) {
    int wave = threadIdx.x >> 6, lane = threadIdx.x & 63;
    int e = blockIdx.x * 4 + wave;
    if (e >= N_EDGES) return;
    int s = src[e], d = dst[e], r = rel[e];
    float2 hv = *(const float2*)(h + (size_t)s * F + lane * 2);
    float2 gv = *(const float2*)(gw + r * F + lane * 2);
    float p = hv.x * gv.x + hv.y * gv.y;
    #pragma unroll
    for (int off = 32; off; off >>= 1) p += __shfl_xor(p, off);
    float scale = norm[e] * sigmoidf(p);
    const float* wr = W + ((size_t)r << 14);
    float a0 = 0.f, a1 = 0.f;
    for (int i2 = 0; i2 < 64; ++i2) {
        float x0 = __shfl(hv.x, i2), x1 = __shfl(hv.y, i2);
        a0 += x0 * wr[(2 * i2) * F + lane]      + x1 * wr[(2 * i2 + 1) * F + lane];
        a1 += x0 * wr[(2 * i2) * F + 64 + lane] + x1 * wr[(2 * i2 + 1) * F + 64 + lane];
    }
    unsafeAtomicAdd(out + (size_t)d * F + lane,      a0 * scale);
    unsafeAtomicAdd(out + (size_t)d * F + 64 + lane, a1 * scale);
}

__global__ void k_final_fb(const float* __restrict__ h, const float* __restrict__ LW,
                           const float* __restrict__ bias, float* __restrict__ out) {
    int wave = threadIdx.x >> 6, lane = threadIdx.x & 63;
    int n = blockIdx.x * 4 + wave;
    if (n >= N_NODES) return;
    float2 hv = *(const float2*)(h + (size_t)n * F + lane * 2);
    float a0 = 0.f, a1 = 0.f;
    for (int i2 = 0; i2 < 64; ++i2) {
        float x0 = __shfl(hv.x, i2), x1 = __shfl(hv.y, i2);
        a0 += x0 * LW[(2 * i2) * F + lane]      + x1 * LW[(2 * i2 + 1) * F + lane];
        a1 += x0 * LW[(2 * i2) * F + 64 + lane] + x1 * LW[(2 * i2 + 1) * F + 64 + lane];
    }
    float* op = out + (size_t)n * F;
    op[lane]      = fmaxf(op[lane]      + bias[lane]      + a0, 0.f);
    op[64 + lane] = fmaxf(op[64 + lane] + bias[64 + lane] + a1, 0.f);
}

extern "C" void kernel_launch(void* const* d_in, const int* in_sizes, int n_in,
                              void* d_out, int out_size, void* d_ws, size_t ws_size,
                              hipStream_t stream) {
    const float* h    = (const float*)d_in[0];
    const float* W    = (const float*)d_in[1];
    const float* gw   = (const float*)d_in[2];
    const float* bias = (const float*)d_in[3];
    const float* lw   = (const float*)d_in[4];
    const float* norm = (const float*)d_in[5];
    const int* src    = (const int*)d_in[6];
    const int* dst    = (const int*)d_in[7];
    const int* rel    = (const int*)d_in[8];
    float* out = (float*)d_out;

    if (ws_size >= WS_NEED) {
        unsigned short* Wt   = (unsigned short*)((char*)d_ws + WT_OFF);
        unsigned short* h2   = (unsigned short*)((char*)d_ws + H2_OFF);
        float*          gate = (float*)((char*)d_ws + GATE_OFF);
        int*            cnt  = (int*)((char*)d_ws + CNT_OFF);
        int*            excl = (int*)((char*)d_ws + EXCL_OFF);
        int*            bsum = (int*)((char*)d_ws + BSUM_OFF);
        int2*           rec  = (int2*)((char*)d_ws + REC_OFF);

        hipMemsetAsync(cnt, 0, 400128 * sizeof(int), stream);
        k_prep_w<<<576, 256, 0, stream>>>(W, lw, Wt);
        k_prep<<<12500, 256, 0, stream>>>(h, gw, dst, rel, h2, gate, cnt);
        k_s1<<<NBS1, 256, 0, stream>>>(cnt, excl, bsum);
        k_s2<<<1, 256, 0, stream>>>(bsum);
        k_scatter<<<2344, 256, 0, stream>>>(src, dst, rel, norm, gate, excl, bsum, cnt, rec);
        k_fused<<<782, 1024, 0, stream>>>(h2, Wt, rec, excl, bsum, bias, out);
    } else {
        hipMemsetAsync(d_out, 0, (size_t)out_size * sizeof(float), stream);
        k_edges_fb<<<150000, 256, 0, stream>>>(h, W, gw, norm, src, dst, rel, out);
        k_final_fb<<<12500, 256, 0, stream>>>(h, lw, bias, out);
    }
}